// Round 1
// baseline (117.288 us; speedup 1.0000x reference)
//
#include <hip/hip_runtime.h>
#include <math.h>

// Circle GIoU loss, summed over N pairs.
// x, y: (N,3) float32 row-major [cx, cy, r]. Output: scalar float32 sum.
//
// R7: R6 math (trans-op diet, fast_acos, shared sqrt(h2)) + load-pattern fix:
// global loads are now UNIT-STRIDE float4 (each instruction = 64 lanes x 16 B
// contiguous), staged through a per-wave LDS transpose. Previous version read
// float4 at 48 B lane stride (3x cache-line touches per instruction). The LDS
// read-back at byte offset lane*48 maps lane-groups to disjoint 4-bank groups
// (48*8 = 384 ≡ 0 mod 128 B) — minimal 8 dwords/bank, conflict-free, no pad.
// DS ops are in-order per wave -> single-buffered LDS reuse across the two
// batches needs no __syncthreads. Circle->thread mapping (and thus summation
// order / bitwise result) identical to R6.
// NOTE: total dur_us carries ~89 us of fixed harness reset cost
// (268 MB d_ws poison + input restores) — controllable part is stage1+2.

#define EPSF   1e-07f
#define ACLIPF (1.0f - 1e-06f)
#define PIF    3.14159265358979323846f

__device__ __forceinline__ float frcp(float x)   { return __builtin_amdgcn_rcpf(x); }
__device__ __forceinline__ float fsqrt(float x)  { return __builtin_amdgcn_sqrtf(x); }
__device__ __forceinline__ float frsqrt(float x) { return __builtin_amdgcn_rsqf(x); }

// A&S 4.4.45: acos(x) ~ sqrt(1-x)*poly(x) on [0,1]; abs err < 6.7e-5
__device__ __forceinline__ float fast_acos_pos(float x) {   // requires x >= 0
    float p = fmaf(fmaf(fmaf(-0.0187293f, x, 0.0742610f), x, -0.2121144f), x, 1.5707288f);
    return fsqrt(1.0f - x) * p;
}
__device__ __forceinline__ float fast_acos(float x) {
    float ax = fabsf(x);
    float r = fast_acos_pos(ax);
    return x < 0.0f ? PIF - r : r;
}

__device__ __forceinline__ float circle_giou(float cx0, float cy0, float r0,
                                             float cx1, float cy1, float r1) {
    float dx = cx0 - cx1, dy = cy0 - cy1;
    float d2 = fmaxf(fmaf(dx, dx, dy * dy), EPSF);       // matches ref's max(d2,EPS) under sqrt
    float rmax = fmaxf(r0, r1), rmin = fminf(r0, r1);
    float rdiff = rmax - rmin, rsum = r0 + r1;
    float rdiff2 = rdiff * rdiff, rsum2 = rsum * rsum;

    // squared-distance comparisons (all quantities >= 0)
    bool lens      = (d2 < rsum2) && (d2 > rdiff2);
    bool contained = (d2 <= rdiff2);

    float invd = frsqrt(d2);          // 1/d
    float d    = d2 * invd;           // sqrt(d2)

    float r0s = r0 * r0, r1s = r1 * r1;
    // denominators 2*d*r > 0 always (d >= 3.16e-4, r > 0 a.s.); clamp after is enough
    float inv0 = frcp(2.0f * d * r0);
    float inv1 = frcp(2.0f * d * r1);
    float cos0 = fminf(fmaxf((d2 + r0s - r1s) * inv0, -ACLIPF), ACLIPF);
    float cos1 = fminf(fmaxf((d2 + r1s - r0s) * inv1, -ACLIPF), ACLIPF);

    // t = (rsum2-d2)*(d2-rdiff2); share sqrt(h2) with hull term
    float h2  = d2 - rdiff2;
    float sh2 = fsqrt(fmaxf(h2, EPSF));                  // sqrt(h2), valid when !contained
    float st  = fsqrt(fmaxf(rsum2 - d2, EPSF)) * sh2;    // = sqrt(t) when lens

    float lens_area = r0s * fast_acos(cos0) + r1s * fast_acos(cos1) - 0.5f * st;
    float inter = lens ? lens_area : (contained ? PIF * rmin * rmin : 0.0f);
    float uni = PIF * (r0s + r1s) - inter;
    float iou = inter * frcp(fmaxf(uni, EPSF));

    float alpha = fast_acos_pos(fminf(rdiff * invd, ACLIPF));   // arg in [0, ACLIP]
    float hull_open = rmax * rmax * (PIF - alpha) + rmin * rmin * alpha
                      + (rmax + rmin) * sh2;
    float hull = contained ? PIF * rmax * rmax : hull_open;

    return 1.0f - (iou - (hull - uni) * frcp(fmaxf(hull, EPSF)));
}

__device__ __forceinline__ float giou4(float4 xa, float4 xb, float4 xc,
                                       float4 ya, float4 yb, float4 yc) {
    float s = 0.0f;
    s += circle_giou(xa.x, xa.y, xa.z,  ya.x, ya.y, ya.z);
    s += circle_giou(xa.w, xb.x, xb.y,  ya.w, yb.x, yb.y);
    s += circle_giou(xb.z, xb.w, xc.x,  yb.z, yb.w, yc.x);
    s += circle_giou(xc.y, xc.z, xc.w,  yc.y, yc.z, yc.w);
    return s;
}

__global__ __launch_bounds__(256)
void GIOULOSS_19524921327670_stage1(const float4* __restrict__ x4,
                                    const float4* __restrict__ y4,
                                    float* __restrict__ partial, int nwaves) {
    // Per-wave staging: [wave][x/y][192 float4]  (24 KiB / block)
    __shared__ float4 lds[4][2][192];

    const int lane = threadIdx.x & 63;
    const int wave = threadIdx.x >> 6;
    const int W    = (blockIdx.x << 2) + wave;   // global wave id
    const int b0   = W * 192;                    // batch-0 float4 base
    const int b1   = (W + nwaves) * 192;         // batch-1: second half of array

    // Issue ALL 12 global loads up-front; every instruction is 64x16B contiguous.
    float4 xa0 = x4[b0 + lane], xb0 = x4[b0 + 64 + lane], xc0 = x4[b0 + 128 + lane];
    float4 ya0 = y4[b0 + lane], yb0 = y4[b0 + 64 + lane], yc0 = y4[b0 + 128 + lane];
    float4 xa1 = x4[b1 + lane], xb1 = x4[b1 + 64 + lane], xc1 = x4[b1 + 128 + lane];
    float4 ya1 = y4[b1 + lane], yb1 = y4[b1 + 64 + lane], yc1 = y4[b1 + 128 + lane];

    float4* lx = &lds[wave][0][0];
    float4* ly = &lds[wave][1][0];
    // Read-back pointers: 12 floats (= 4 circles) per lane, 16B-aligned (48*l % 16 == 0).
    const float4* tx = (const float4*)((const float*)lx + lane * 12);
    const float4* ty = (const float4*)((const float*)ly + lane * 12);

    // Batch 0: linear ds_write_b128, then 3+3 ds_read_b128 per lane.
    lx[lane] = xa0; lx[64 + lane] = xb0; lx[128 + lane] = xc0;
    ly[lane] = ya0; ly[64 + lane] = yb0; ly[128 + lane] = yc0;
    float acc = giou4(tx[0], tx[1], tx[2], ty[0], ty[1], ty[2]);

    // Batch 1: DS ops are in-order within a wave -> safe single-buffer reuse.
    lx[lane] = xa1; lx[64 + lane] = xb1; lx[128 + lane] = xc1;
    ly[lane] = ya1; ly[64 + lane] = yb1; ly[128 + lane] = yc1;
    acc += giou4(tx[0], tx[1], tx[2], ty[0], ty[1], ty[2]);

    #pragma unroll
    for (int off = 32; off > 0; off >>= 1)
        acc += __shfl_down(acc, off, 64);

    __shared__ float wave_sums[4];
    if (lane == 0) wave_sums[wave] = acc;
    __syncthreads();
    if (threadIdx.x == 0)
        partial[blockIdx.x] = wave_sums[0] + wave_sums[1] + wave_sums[2] + wave_sums[3];
}

// Sums 2048 block partials with one 256-thread block.
__global__ __launch_bounds__(256)
void GIOULOSS_19524921327670_stage2(const float* __restrict__ partial,
                                    float* __restrict__ out) {
    const float4* p4 = (const float4*)partial;   // 2048 floats = 512 float4
    float4 a = p4[threadIdx.x];
    float4 b = p4[threadIdx.x + 256];
    float acc = (a.x + a.y) + (a.z + a.w) + (b.x + b.y) + (b.z + b.w);

    #pragma unroll
    for (int off = 32; off > 0; off >>= 1)
        acc += __shfl_down(acc, off, 64);

    __shared__ float wave_sums[4];
    int lane = threadIdx.x & 63;
    int wave = threadIdx.x >> 6;
    if (lane == 0) wave_sums[wave] = acc;
    __syncthreads();
    if (threadIdx.x == 0)
        out[0] = wave_sums[0] + wave_sums[1] + wave_sums[2] + wave_sums[3];
}

extern "C" void kernel_launch(void* const* d_in, const int* in_sizes, int n_in,
                              void* d_out, int out_size, void* d_ws, size_t ws_size,
                              hipStream_t stream) {
    const float4* x4 = (const float4*)d_in[0];
    const float4* y4 = (const float4*)d_in[1];
    float* out = (float*)d_out;
    float* partial = (float*)d_ws;

    int n = in_sizes[0] / 3;      // 4194304 circle pairs
    int ngroups = n / 4;          // 1048576 groups of 4 circles (3 float4 each)
    int nwaves = ngroups / 128;   // 8192 waves; each wave: 64 groups x 2 batches
    int block = 256;
    int grid = nwaves / 4;        // 2048 blocks -> 2048 partials

    GIOULOSS_19524921327670_stage1<<<grid, block, 0, stream>>>(x4, y4, partial, nwaves);
    GIOULOSS_19524921327670_stage2<<<1, block, 0, stream>>>(partial, out);
}

// Round 2
// 115.226 us; speedup vs baseline: 1.0179x; 1.0179x over previous
//
#include <hip/hip_runtime.h>
#include <math.h>

// Circle GIoU loss, summed over N pairs.
// x, y: (N,3) float32 row-major [cx, cy, r]. Output: scalar float32 sum.
//
// R8: revert R7's LDS transpose (regressed 114.8 -> 117.3 us: stride-48
// float4 loads already coalesce fully via MSHR merge across the 3-instr
// 3KB/wave window; LDS round-trip was pure overhead). Back to R6 direct
// loads, but restructured for occupancy: SEQUENTIAL two-batch loads (6
// float4 live instead of 12) + __launch_bounds__(256, 8) forcing VGPR<=64
// -> 8 waves/SIMD (was ~6 with 12 up-front loads at ~75+ VGPR). Full-TLP
// latency hiding replaces per-thread ILP prefetch, which is unnecessary
// for a memory-bound kernel at full occupancy.
// Element->thread mapping and accumulation order identical to R6
// (g0 = t, g1 = t + nthreads; acc = batch0 + batch1) -> bitwise-same sum.
// NOTE: total dur_us carries ~89 us of fixed harness reset cost
// (268 MB d_ws poison + input restores) — controllable part is stage1+2.

#define EPSF   1e-07f
#define ACLIPF (1.0f - 1e-06f)
#define PIF    3.14159265358979323846f

__device__ __forceinline__ float frcp(float x)   { return __builtin_amdgcn_rcpf(x); }
__device__ __forceinline__ float fsqrt(float x)  { return __builtin_amdgcn_sqrtf(x); }
__device__ __forceinline__ float frsqrt(float x) { return __builtin_amdgcn_rsqf(x); }

// A&S 4.4.45: acos(x) ~ sqrt(1-x)*poly(x) on [0,1]; abs err < 6.7e-5
__device__ __forceinline__ float fast_acos_pos(float x) {   // requires x >= 0
    float p = fmaf(fmaf(fmaf(-0.0187293f, x, 0.0742610f), x, -0.2121144f), x, 1.5707288f);
    return fsqrt(1.0f - x) * p;
}
__device__ __forceinline__ float fast_acos(float x) {
    float ax = fabsf(x);
    float r = fast_acos_pos(ax);
    return x < 0.0f ? PIF - r : r;
}

__device__ __forceinline__ float circle_giou(float cx0, float cy0, float r0,
                                             float cx1, float cy1, float r1) {
    float dx = cx0 - cx1, dy = cy0 - cy1;
    float d2 = fmaxf(fmaf(dx, dx, dy * dy), EPSF);       // matches ref's max(d2,EPS) under sqrt
    float rmax = fmaxf(r0, r1), rmin = fminf(r0, r1);
    float rdiff = rmax - rmin, rsum = r0 + r1;
    float rdiff2 = rdiff * rdiff, rsum2 = rsum * rsum;

    // squared-distance comparisons (all quantities >= 0)
    bool lens      = (d2 < rsum2) && (d2 > rdiff2);
    bool contained = (d2 <= rdiff2);

    float invd = frsqrt(d2);          // 1/d
    float d    = d2 * invd;           // sqrt(d2)

    float r0s = r0 * r0, r1s = r1 * r1;
    // denominators 2*d*r > 0 always (d >= 3.16e-4, r > 0 a.s.); clamp after is enough
    float inv0 = frcp(2.0f * d * r0);
    float inv1 = frcp(2.0f * d * r1);
    float cos0 = fminf(fmaxf((d2 + r0s - r1s) * inv0, -ACLIPF), ACLIPF);
    float cos1 = fminf(fmaxf((d2 + r1s - r0s) * inv1, -ACLIPF), ACLIPF);

    // t = (rsum2-d2)*(d2-rdiff2); share sqrt(h2) with hull term
    float h2  = d2 - rdiff2;
    float sh2 = fsqrt(fmaxf(h2, EPSF));                  // sqrt(h2), valid when !contained
    float st  = fsqrt(fmaxf(rsum2 - d2, EPSF)) * sh2;    // = sqrt(t) when lens

    float lens_area = r0s * fast_acos(cos0) + r1s * fast_acos(cos1) - 0.5f * st;
    float inter = lens ? lens_area : (contained ? PIF * rmin * rmin : 0.0f);
    float uni = PIF * (r0s + r1s) - inter;
    float iou = inter * frcp(fmaxf(uni, EPSF));

    float alpha = fast_acos_pos(fminf(rdiff * invd, ACLIPF));   // arg in [0, ACLIP]
    float hull_open = rmax * rmax * (PIF - alpha) + rmin * rmin * alpha
                      + (rmax + rmin) * sh2;
    float hull = contained ? PIF * rmax * rmax : hull_open;

    return 1.0f - (iou - (hull - uni) * frcp(fmaxf(hull, EPSF)));
}

__device__ __forceinline__ float giou4(float4 xa, float4 xb, float4 xc,
                                       float4 ya, float4 yb, float4 yc) {
    float s = 0.0f;
    s += circle_giou(xa.x, xa.y, xa.z,  ya.x, ya.y, ya.z);
    s += circle_giou(xa.w, xb.x, xb.y,  ya.w, yb.x, yb.y);
    s += circle_giou(xb.z, xb.w, xc.x,  yb.z, yb.w, yc.x);
    s += circle_giou(xc.y, xc.z, xc.w,  yc.y, yc.z, yc.w);
    return s;
}

__global__ __launch_bounds__(256, 8)   // force VGPR<=64 -> 8 waves/SIMD
void GIOULOSS_19524921327670_stage1(const float4* __restrict__ x4,
                                    const float4* __restrict__ y4,
                                    float* __restrict__ partial, int nthreads) {
    int t = blockIdx.x * blockDim.x + threadIdx.x;
    int g0 = t, g1 = t + nthreads;   // two coalesced halves

    // Batch 0: 6 float4 live (24 VGPR) -> compute -> regs freed.
    float4 xa0 = x4[3 * g0 + 0], xb0 = x4[3 * g0 + 1], xc0 = x4[3 * g0 + 2];
    float4 ya0 = y4[3 * g0 + 0], yb0 = y4[3 * g0 + 1], yc0 = y4[3 * g0 + 2];
    float acc = giou4(xa0, xb0, xc0, ya0, yb0, yc0);

    // Batch 1 (TLP at 8 waves/SIMD hides this latency; no ILP prefetch needed).
    float4 xa1 = x4[3 * g1 + 0], xb1 = x4[3 * g1 + 1], xc1 = x4[3 * g1 + 2];
    float4 ya1 = y4[3 * g1 + 0], yb1 = y4[3 * g1 + 1], yc1 = y4[3 * g1 + 2];
    acc += giou4(xa1, xb1, xc1, ya1, yb1, yc1);

    #pragma unroll
    for (int off = 32; off > 0; off >>= 1)
        acc += __shfl_down(acc, off, 64);

    __shared__ float wave_sums[4];
    int lane = threadIdx.x & 63;
    int wave = threadIdx.x >> 6;
    if (lane == 0) wave_sums[wave] = acc;
    __syncthreads();
    if (threadIdx.x == 0)
        partial[blockIdx.x] = wave_sums[0] + wave_sums[1] + wave_sums[2] + wave_sums[3];
}

// Sums 2048 block partials with one 256-thread block.
__global__ __launch_bounds__(256)
void GIOULOSS_19524921327670_stage2(const float* __restrict__ partial,
                                    float* __restrict__ out) {
    const float4* p4 = (const float4*)partial;   // 2048 floats = 512 float4
    float4 a = p4[threadIdx.x];
    float4 b = p4[threadIdx.x + 256];
    float acc = (a.x + a.y) + (a.z + a.w) + (b.x + b.y) + (b.z + b.w);

    #pragma unroll
    for (int off = 32; off > 0; off >>= 1)
        acc += __shfl_down(acc, off, 64);

    __shared__ float wave_sums[4];
    int lane = threadIdx.x & 63;
    int wave = threadIdx.x >> 6;
    if (lane == 0) wave_sums[wave] = acc;
    __syncthreads();
    if (threadIdx.x == 0)
        out[0] = wave_sums[0] + wave_sums[1] + wave_sums[2] + wave_sums[3];
}

extern "C" void kernel_launch(void* const* d_in, const int* in_sizes, int n_in,
                              void* d_out, int out_size, void* d_ws, size_t ws_size,
                              hipStream_t stream) {
    const float4* x4 = (const float4*)d_in[0];
    const float4* y4 = (const float4*)d_in[1];
    float* out = (float*)d_out;
    float* partial = (float*)d_ws;

    int n = in_sizes[0] / 3;      // 4194304 circle pairs
    int ngroups = n / 4;          // 1048576 groups of 4
    int nthreads = ngroups / 2;   // 524288 threads, 2 groups (8 elems) each
    int block = 256;
    int grid = nthreads / block;  // 2048 blocks -> 2048 partials

    GIOULOSS_19524921327670_stage1<<<grid, block, 0, stream>>>(x4, y4, partial, nthreads);
    GIOULOSS_19524921327670_stage2<<<1, block, 0, stream>>>(partial, out);
}